// Round 15
// baseline (684.692 us; speedup 1.0000x reference)
//
#include <hip/hip_runtime.h>
#include <stdint.h>

// B=4096, T=1, N=8, H=512, NUM_COMMS=8, COMM_SIZE=64, VOCAB=512
#define KDIM   512
#define NDIM   512
#define NGRP   8
#define CSZ    64
#define VOCABN 512
#define M2     262144
#define OUT_Q  16777216u
#define GAP_T  0.02f
#define VQROWS 128             // rows per block
#define VQGRID (M2 / VQROWS)   // 2048
#define CCH    64              // codes per LDS chunk
#define NCHUNK (VOCABN / CCH)  // 8
// d_out: [0,16777216) comm_output ; [16777216] vq_loss ; [+1,+32768) log_probs

// ---------------------------------------------------------------------------
__global__ __launch_bounds__(256) void prep_sumc2(
    const float* __restrict__ cb, float* __restrict__ sumc2)
{
  const int v = blockIdx.x * 256 + threadIdx.x;
  if (v < VOCABN) {
    float s = 0.f;
#pragma unroll
    for (int c = 0; c < CSZ; ++c) s = fmaf(cb[v * CSZ + c], cb[v * CSZ + c], s);
    sumc2[v] = s;
  }
}

// ---------------------------------------------------------------------------
// f32 GEMM: logits = X @ W + b -> out (128x128x32 tiles, 8x8/thread)
// ---------------------------------------------------------------------------
constexpr int BM = 128, BN = 128, BK = 32;

__global__ __launch_bounds__(256) void gemm_bias_kernel(
    const float* __restrict__ X, const float* __restrict__ W,
    const float* __restrict__ bias, float* __restrict__ logits)
{
  __shared__ float As[BK][BM + 4];   // 16.9 KB
  __shared__ float Bs[BK][BN];       // 16.4 KB
  const int tid = threadIdx.x;
  const int bx = blockIdx.x, by = blockIdx.y;
  const int tx = tid & 15, ty = tid >> 4;
  const int ar = tid >> 1, ak = (tid & 1) * 16;    // A: row, k-offset (16 floats)
  const int bkr = tid >> 3, bc = (tid & 7) * 16;   // B: k-row, col (16 floats)

  const float* Xb = X + (size_t)(by * BM) * KDIM;
  const float* Wb = W + bx * BN;

  float acc[8][8];
#pragma unroll
  for (int i = 0; i < 8; ++i)
#pragma unroll
    for (int j = 0; j < 8; ++j) acc[i][j] = 0.f;

  for (int k0 = 0; k0 < KDIM; k0 += BK) {
    float4 a[4], b[4];
#pragma unroll
    for (int q = 0; q < 4; ++q) {
      a[q] = *(const float4*)(Xb + (size_t)ar * KDIM + k0 + ak + q * 4);
      b[q] = *(const float4*)(Wb + (size_t)(k0 + bkr) * NDIM + bc + q * 4);
    }
    if (k0) __syncthreads();
#pragma unroll
    for (int q = 0; q < 4; ++q) {
      As[ak + q * 4 + 0][ar] = a[q].x; As[ak + q * 4 + 1][ar] = a[q].y;
      As[ak + q * 4 + 2][ar] = a[q].z; As[ak + q * 4 + 3][ar] = a[q].w;
      *(float4*)&Bs[bkr][bc + q * 4] = b[q];
    }
    __syncthreads();
#pragma unroll
    for (int k = 0; k < BK; ++k) {
      float av[8], bv[8];
      *(float4*)&av[0] = *(const float4*)&As[k][ty * 8];
      *(float4*)&av[4] = *(const float4*)&As[k][ty * 8 + 4];
      *(float4*)&bv[0] = *(const float4*)&Bs[k][tx * 8];
      *(float4*)&bv[4] = *(const float4*)&Bs[k][tx * 8 + 4];
#pragma unroll
      for (int i = 0; i < 8; ++i)
#pragma unroll
        for (int j = 0; j < 8; ++j)
          acc[i][j] = fmaf(av[i], bv[j], acc[i][j]);
    }
  }

  float bvv[8];
  *(float4*)&bvv[0] = *(const float4*)(bias + bx * BN + tx * 8);
  *(float4*)&bvv[4] = *(const float4*)(bias + bx * BN + tx * 8 + 4);
#pragma unroll
  for (int i = 0; i < 8; ++i) {
    const int row = by * BM + ty * 8 + i;
    float o[8];
#pragma unroll
    for (int j = 0; j < 8; ++j) o[j] = __fadd_rn(acc[i][j], bvv[j]);
    float* orow = logits + (size_t)row * NDIM + bx * BN + tx * 8;
    *(float4*)orow = *(float4*)&o[0];
    *(float4*)(orow + 4) = *(float4*)&o[4];
  }
}

// ---------------------------------------------------------------------------
// VQ GEMM-dataflow v2: fls[128][64] + cbt[64][64], both XOR-swizzled
// (col_quad ^= row&7 -> conflict-free fv, 2-way cv). Chunk prefetch into regs
// overlaps global latency with FMA. Cross-tx top-2 via shfl_xor butterfly
// (removes 24KB LDS reduce). LDS ~52KB -> 3 blocks/CU.
// ---------------------------------------------------------------------------
__global__ __launch_bounds__(256, 3) void vq_tile_kernel(
    float* __restrict__ rows,          // [M2,64] logits in / q out (d_out alias)
    const float* __restrict__ cb, const float* __restrict__ sumc2,
    double* __restrict__ partials, int* __restrict__ wlist,
    int* __restrict__ wcount)
{
  __shared__ float fls[VQROWS * CSZ];   // 32 KB (swizzled)
  __shared__ float cbt[CCH * CSZ];      // 16 KB (swizzled)
  __shared__ float scs[CCH];
  __shared__ int   rowi[VQROWS];
  __shared__ int   rowdf[VQROWS];
  __shared__ double lred[256];

  const int tid = threadIdx.x;
  const int tx = tid & 15, ty = tid >> 4;
  const int rsw = ty & 7, csw = tx & 7;
  const size_t mbase = (size_t)blockIdx.x * VQROWS;

  // stage logits rows (contiguous loads, swizzled LDS writes)
  float4 fstg[8];
#pragma unroll
  for (int t = 0; t < 8; ++t)
    fstg[t] = *(const float4*)(rows + mbase * CSZ + (size_t)(t * 256 + tid) * 4);
  float4 cstg[4];
#pragma unroll
  for (int t = 0; t < 4; ++t)
    cstg[t] = *(const float4*)(cb + (size_t)(t * 256 + tid) * 4);   // chunk 0
#pragma unroll
  for (int t = 0; t < 8; ++t) {
    const int idx = t * 256 + tid;
    const int r = idx >> 4, c4 = idx & 15;
    *(float4*)&fls[r * CSZ + ((c4 ^ (r & 7)) << 2)] = fstg[t];
  }

  float b1[8], b2[8]; int idx1[8];
#pragma unroll
  for (int i = 0; i < 8; ++i) {
    b1[i] = __builtin_inff(); b2[i] = __builtin_inff(); idx1[i] = VOCABN;
  }

  for (int chunk = 0; chunk < NCHUNK; ++chunk) {
    __syncthreads();                    // prev chunk consumers done (also fls)
#pragma unroll
    for (int t = 0; t < 4; ++t) {
      const int idx = t * 256 + tid;
      const int r = idx >> 4, c4 = idx & 15;
      *(float4*)&cbt[r * CSZ + ((c4 ^ (r & 7)) << 2)] = cstg[t];
    }
    if (tid < CCH) scs[tid] = sumc2[chunk * CCH + tid];
    __syncthreads();
    if (chunk < NCHUNK - 1) {           // prefetch next chunk under compute
#pragma unroll
      for (int t = 0; t < 4; ++t)
        cstg[t] = *(const float4*)(cb + (size_t)(chunk + 1) * CCH * CSZ
                                      + (size_t)(t * 256 + tid) * 4);
    }

    float acc[8][4];
#pragma unroll
    for (int i = 0; i < 8; ++i)
#pragma unroll
      for (int j = 0; j < 4; ++j) acc[i][j] = 0.f;

    for (int k4 = 0; k4 < 16; ++k4) {
      const int fo = (k4 ^ rsw) << 2;   // lane-varying (ty&7) -> conflict-free
      const int co = (k4 ^ csw) << 2;   // lane-varying (tx&7) -> 2-way (free)
      float4 fv[8], cv[4];
#pragma unroll
      for (int i = 0; i < 8; ++i)
        fv[i] = *(const float4*)&fls[(ty + i * 16) * CSZ + fo];
#pragma unroll
      for (int j = 0; j < 4; ++j)
        cv[j] = *(const float4*)&cbt[(tx + j * 16) * CSZ + co];
#pragma unroll
      for (int i = 0; i < 8; ++i)
#pragma unroll
        for (int j = 0; j < 4; ++j) {
          acc[i][j] = fmaf(fv[i].x, cv[j].x, acc[i][j]);
          acc[i][j] = fmaf(fv[i].y, cv[j].y, acc[i][j]);
          acc[i][j] = fmaf(fv[i].z, cv[j].z, acc[i][j]);
          acc[i][j] = fmaf(fv[i].w, cv[j].w, acc[i][j]);
        }
    }

#pragma unroll
    for (int j = 0; j < 4; ++j) {
      const int v = chunk * CCH + tx + j * 16;   // ascending within thread
      const float sc = scs[tx + j * 16];
#pragma unroll
      for (int i = 0; i < 8; ++i) {
        const float d = fmaf(-2.0f, acc[i][j], sc);
        const bool w1 = d < b1[i];
        const bool w2 = d < b2[i];
        b2[i] = w1 ? b1[i] : (w2 ? d : b2[i]);
        idx1[i] = w1 ? v : idx1[i];
        b1[i] = w1 ? d : b1[i];
      }
    }
  }

  // cross-tx top-2 merge: shfl_xor butterfly, lexicographic (d, idx) first-min
#pragma unroll
  for (int i = 0; i < 8; ++i) {
    float d1 = b1[i], d2 = b2[i]; int j1 = idx1[i];
#pragma unroll
    for (int s = 1; s < 16; s <<= 1) {
      const float od1 = __shfl_xor(d1, s, 64);
      const float od2 = __shfl_xor(d2, s, 64);
      const int   oj1 = __shfl_xor(j1, s, 64);
      if (od1 < d1 || (od1 == d1 && oj1 < j1)) {
        d2 = fminf(d1, od2); d1 = od1; j1 = oj1;
      } else {
        d2 = fminf(d2, od1);
      }
    }
    if (tx == 0) {
      const int r = ty + i * 16;
      rowi[r] = j1;
      const bool df = (d2 - d1) < GAP_T;
      rowdf[r] = df ? 1 : 0;
      if (df) { const int s2 = atomicAdd(wcount, 1); wlist[s2] = (int)mbase + r; }
    }
  }
  __syncthreads();

  // gather q, write out (coalesced), f64 loss over confident rows
  double ls = 0.0;
#pragma unroll
  for (int t = 0; t < 8; ++t) {
    const int idx = t * 256 + tid;
    const int r = idx >> 4, c4 = idx & 15;
    const int qi = rowi[r];
    const float4 q = *(const float4*)(cb + (size_t)qi * CSZ + c4 * 4);
    const float4 fv = *(const float4*)&fls[r * CSZ + ((c4 ^ (r & 7)) << 2)];
    if (!rowdf[r]) {
      double e;
      e = (double)q.x - (double)fv.x; ls = fma(e, e, ls);
      e = (double)q.y - (double)fv.y; ls = fma(e, e, ls);
      e = (double)q.z - (double)fv.z; ls = fma(e, e, ls);
      e = (double)q.w - (double)fv.w; ls = fma(e, e, ls);
    }
    *(float4*)(rows + (mbase + r) * CSZ + c4 * 4) = q;
  }

  lred[tid] = ls;
  __syncthreads();
#pragma unroll
  for (int off = 128; off > 0; off >>= 1) {
    if (tid < off) lred[tid] += lred[tid + off];
    __syncthreads();
  }
  if (tid == 0) partials[blockIdx.x] = lred[0];
}

// ---------------------------------------------------------------------------
// f64 recheck: coalesced logits recompute, distances 2 codes/thread,
// parallel top-2 tree-reduce, rewrite q, corr[m], gap key.
// ---------------------------------------------------------------------------
__global__ __launch_bounds__(256) void recheck_kernel(
    const float* __restrict__ X, const float* __restrict__ W,
    const float* __restrict__ bias, const float* __restrict__ cb,
    const int* __restrict__ wlist, const int* __restrict__ wcount,
    float* __restrict__ out, double* __restrict__ corr,
    unsigned long long* __restrict__ gkey)
{
  __shared__ double part[4][CSZ];
  __shared__ double fld[CSZ];
  __shared__ double rd1[256], rd2[256];
  __shared__ int    ri1[256];
  __shared__ int    si1;

  const int tid = threadIdx.x;
  const int c = tid & 63, p = tid >> 6;
  const int n = *wcount;
  for (int w = blockIdx.x; w < n; w += gridDim.x) {
    const int m = wlist[w];
    const int r = m >> 3, g = m & 7;
    {
      double s = 0.0;
      const float* xr = X + (size_t)r * KDIM + p * 128;
      const float* wp = W + (size_t)(p * 128) * NDIM + g * CSZ + c;
      for (int h = 0; h < 128; ++h)
        s = fma((double)xr[h], (double)wp[(size_t)h * NDIM], s);
      part[p][c] = s;
    }
    __syncthreads();
    if (tid < CSZ)
      fld[tid] = ((part[0][tid] + part[1][tid]) + (part[2][tid] + part[3][tid]))
                 + (double)bias[g * CSZ + tid];
    __syncthreads();
    double d1 = 1e300, d2 = 1e300; int i1 = 0;
#pragma unroll
    for (int q = 0; q < 2; ++q) {
      const int v = tid + q * 256;
      const float* cr = cb + (size_t)v * CSZ;
      double s2 = 0.0;
#pragma unroll
      for (int cc = 0; cc < CSZ; ++cc) {
        const double e = fld[cc] - (double)cr[cc];
        s2 = fma(e, e, s2);
      }
      if (s2 < d1) { d2 = d1; d1 = s2; i1 = v; }
      else if (s2 < d2) d2 = s2;
    }
    rd1[tid] = d1; rd2[tid] = d2; ri1[tid] = i1;
    __syncthreads();
#pragma unroll
    for (int off = 128; off > 0; off >>= 1) {
      if (tid < off) {
        const double a1 = rd1[tid], a2 = rd2[tid];
        const int    ai = ri1[tid];
        const double bb1 = rd1[tid + off], bb2 = rd2[tid + off];
        const int    bi = ri1[tid + off];
        if (bb1 < a1 || (bb1 == a1 && bi < ai)) {
          rd1[tid] = bb1; ri1[tid] = bi;
          rd2[tid] = (a1 < bb2) ? a1 : bb2;
        } else {
          rd2[tid] = (bb1 < a2) ? bb1 : a2;
        }
      }
      __syncthreads();
    }
    if (tid == 0) {
      corr[m] = rd1[0];
      const float gapf = (float)(rd2[0] - rd1[0]);
      atomicMin(gkey, ((unsigned long long)__float_as_uint(gapf) << 32) | (unsigned)m);
      si1 = ri1[0];
    }
    __syncthreads();
    if (tid < CSZ) out[(size_t)m * CSZ + tid] = cb[(size_t)si1 * CSZ + tid];
    __syncthreads();
  }
}

// ---------------------------------------------------------------------------
__global__ __launch_bounds__(256) void corr_reduce(
    const double* __restrict__ corr, double* __restrict__ corrpart)
{
  __shared__ double red[256];
  const int t = threadIdx.x;
  const size_t base = (size_t)blockIdx.x * 1024;
  double s = ((corr[base + t] + corr[base + 256 + t]) +
              (corr[base + 512 + t] + corr[base + 768 + t]));
  red[t] = s;
  __syncthreads();
#pragma unroll
  for (int off = 128; off > 0; off >>= 1) {
    if (t < off) red[t] += red[t + off];
    __syncthreads();
  }
  if (t == 0) corrpart[blockIdx.x] = red[0];
}

// ---------------------------------------------------------------------------
// flip the global min-gap row to its exact runner-up; assemble loss.
// ---------------------------------------------------------------------------
__global__ __launch_bounds__(256) void flip_finalize(
    const float* __restrict__ X, const float* __restrict__ W,
    const float* __restrict__ bias, const float* __restrict__ cb,
    const double* __restrict__ partials,   // [2048]
    const double* __restrict__ corrpart,   // [256]
    const unsigned long long* __restrict__ gkey, float* __restrict__ out)
{
  __shared__ double part[4][CSZ];
  __shared__ double fld[CSZ];
  __shared__ double darr[VOCABN];
  __shared__ double sred[256];
  __shared__ int    sw2;
  __shared__ double sdelta;

  const int tid = threadIdx.x;
  const unsigned long long key = *gkey;
  const float gapf = __uint_as_float((unsigned)(key >> 32));
  const int   mstar = (int)(key & 0xFFFFFFFFu);
  const bool  doflip = (gapf < 1e-4f) && (mstar >= 0) && (mstar < M2);

  const int r = mstar >> 3, g = mstar & 7;
  const int c = tid & 63, p = tid >> 6;
  {
    double s = 0.0;
    const float* xr = X + (size_t)r * KDIM + p * 128;
    const float* wp = W + (size_t)(p * 128) * NDIM + g * CSZ + c;
    for (int h = 0; h < 128; ++h)
      s = fma((double)xr[h], (double)wp[(size_t)h * NDIM], s);
    part[p][c] = s;
  }
  __syncthreads();
  if (tid < CSZ)
    fld[tid] = ((part[0][tid] + part[1][tid]) + (part[2][tid] + part[3][tid]))
               + (double)bias[g * CSZ + tid];
  __syncthreads();
  for (int v = tid; v < VOCABN; v += 256) {
    double s2 = 0.0;
    const float* cr = cb + (size_t)v * CSZ;
#pragma unroll
    for (int cc = 0; cc < CSZ; ++cc) {
      const double e = fld[cc] - (double)cr[cc];
      s2 = fma(e, e, s2);
    }
    darr[v] = s2;
  }
  __syncthreads();
  if (tid == 0) {
    double d1 = darr[0]; int w1 = 0; double d2 = 1e300; int w2 = 0;
    for (int v = 1; v < VOCABN; ++v) {
      const double d = darr[v];
      if (d < d1)      { d2 = d1; w2 = w1; d1 = d; w1 = v; }
      else if (d < d2) { d2 = d;  w2 = v; }
    }
    sw2 = w2; sdelta = d2 - d1;
  }
  __syncthreads();
  if (doflip && tid < CSZ)
    out[(size_t)mstar * CSZ + tid] = cb[(size_t)sw2 * CSZ + tid];

  // loss = 1.25 * (sum(partials[2048]) + sum(corrpart[256]) + delta) / OUT_Q
  double s = 0.0;
#pragma unroll
  for (int k = 0; k < 8; ++k) s += partials[tid + k * 256];
  s += corrpart[tid];
  sred[tid] = s;
  __syncthreads();
#pragma unroll
  for (int off = 128; off > 0; off >>= 1) {
    if (tid < off) sred[tid] += sred[tid + off];
    __syncthreads();
  }
  if (tid == 0) {
    const double total = sred[0] + (doflip ? sdelta : 0.0);
    out[OUT_Q] = (float)(1.25 * (total / (double)OUT_Q));
  }
}

// ---------------------------------------------------------------------------
extern "C" void kernel_launch(void* const* d_in, const int* in_sizes, int n_in,
                              void* d_out, int out_size, void* d_ws, size_t ws_size,
                              hipStream_t stream) {
  const float* X  = (const float*)d_in[0];   // [4096,1,8,512]
  const float* W  = (const float*)d_in[1];   // [512,512]
  const float* b  = (const float*)d_in[2];   // [512]
  const float* cb = (const float*)d_in[3];   // [512,64]
  float* out = (float*)d_out;

  // ws layout (8B-aligned first):
  double* corr     = (double*)d_ws;                       // 262144 f64 = 2 MB
  double* partials = corr + M2;                           // 2048 (vq grid)
  double* corrpart = partials + VQGRID;                   // 256
  unsigned long long* gkey = (unsigned long long*)(corrpart + 256);
  int*    wcount   = (int*)(gkey + 1);                    // 1 (+1 pad)
  int*    wlist    = wcount + 2;                          // 262144 ints = 1 MB
  float*  sumc2    = (float*)(wlist + M2);                // 512 f32

  hipMemsetAsync(out + OUT_Q + 1, 0, 32768 * sizeof(float), stream); // log_probs
  hipMemsetAsync(corr, 0, M2 * sizeof(double), stream);
  hipMemsetAsync(gkey, 0xFF, sizeof(unsigned long long), stream);
  hipMemsetAsync(wcount, 0, sizeof(int), stream);

  prep_sumc2<<<2, 256, 0, stream>>>(cb, sumc2);
  gemm_bias_kernel<<<dim3(4, 256), 256, 0, stream>>>(X, W, b, out);
  vq_tile_kernel<<<VQGRID, 256, 0, stream>>>(out, cb, sumc2, partials, wlist, wcount);
  recheck_kernel<<<1024, 256, 0, stream>>>(X, W, b, cb, wlist, wcount, out, corr, gkey);
  corr_reduce<<<256, 256, 0, stream>>>(corr, corrpart);
  flip_finalize<<<1, 256, 0, stream>>>(X, W, b, cb, partials, corrpart, gkey, out);
}